// Round 1
// 321.592 us; speedup vs baseline: 1.0101x; 1.0101x over previous
//
#include <hip/hip_runtime.h>

// BinaryDense: out = sign(x) @ sign(w). x[8192,4096] f32, w[4096,4096] f32, out f32.
// fp4 e2m1 nibble encoding {-1,0,+1} = {0xA,0x0,0x2}; MX-scaled fp4 MFMA (scales=1.0).
// Round 4: 256x256 tile, 8 waves (wave tile 128x64 -> 0.75 ds_read/mfma instead of 1.0),
// BK=256, global_load_lds staging (no ds_writes, pre-swizzled source + XOR read swizzle),
// double-buffered LDS, one __syncthreads per K-iter (stage issued a full iter ahead).

#define M_DIM 8192
#define K_DIM 4096
#define N_DIM 4096
#define KB2   (K_DIM / 2)      // packed bytes per row = 2048
#define BKB   128              // bytes per row per K-tile (256 nibbles)
#define NKT   (KB2 / BKB)      // 16 K-iterations
#define TILEB (256 * BKB)      // one operand tile = 32 KB
#define BUFB  (2 * TILEB)      // one LDS buffer (A+B) = 64 KB

typedef int   v4i  __attribute__((ext_vector_type(4)));
typedef int   v8i  __attribute__((ext_vector_type(8)));
typedef float v16f __attribute__((ext_vector_type(16)));

__device__ __forceinline__ unsigned int nib4(float x) {
    // fp4 e2m1: +1.0 -> 0b0010, -1.0 -> 0b1010, 0 -> 0b0000
    return x > 0.0f ? 0x2u : (x < 0.0f ? 0xAu : 0x0u);
}

// ---- fused pack: blocks [0, 32768) pack x; blocks [32768, 34816) pack wT ----
__global__ __launch_bounds__(256) void pack_both(const float* __restrict__ x,
                                                 unsigned short* __restrict__ xq,
                                                 const float* __restrict__ w,
                                                 unsigned char* __restrict__ wT) {
    if (blockIdx.x < 32768u) {
        // pack x: 4 floats -> 4 nibbles (one ushort) per thread
        size_t t = (size_t)blockIdx.x * 256 + threadIdx.x;
        float4 f = ((const float4*)x)[t];
        unsigned int v = nib4(f.x) | (nib4(f.y) << 4) | (nib4(f.z) << 8) | (nib4(f.w) << 12);
        xq[t] = (unsigned short)v;
        return;
    }
    // pack wT: w[k][n] f32 -> wT[n][k/2] nibbles, 64k x 128n tile via LDS
    __shared__ unsigned char sT[64][132];
    const unsigned id = blockIdx.x - 32768u;
    const int t  = threadIdx.x;
    const int n0 = (int)(id & 31) * 128;
    const int kb = (int)(id >> 5);
    const int k0 = kb * 64;

    const int cq = t & 31;   // float4 column
    const int r0 = t >> 5;   // 0..7
#pragma unroll
    for (int p = 0; p < 8; ++p) {
        int r = r0 + 8 * p;
        float4 f = *(const float4*)(w + (size_t)(k0 + r) * N_DIM + n0 + cq * 4);
        uchar4 c;
        c.x = (unsigned char)nib4(f.x);
        c.y = (unsigned char)nib4(f.y);
        c.z = (unsigned char)nib4(f.z);
        c.w = (unsigned char)nib4(f.w);
        *(uchar4*)(&sT[r][cq * 4]) = c;
    }
    __syncthreads();

    const int n  = t >> 1;   // 0..127
    const int kq = t & 1;    // 32-k chunk
    union { unsigned char b[16]; int4 v; } u;
#pragma unroll
    for (int j = 0; j < 16; ++j) {
        unsigned lo = sT[kq * 32 + 2 * j][n];
        unsigned hi = sT[kq * 32 + 2 * j + 1][n];
        u.b[j] = (unsigned char)(lo | (hi << 4));
    }
    *(int4*)(wT + (size_t)(n0 + n) * KB2 + (size_t)kb * 32 + kq * 16) = u.v;
}

__device__ __forceinline__ v8i widen(v4i x) {
    v8i r;
    r[0] = x[0]; r[1] = x[1]; r[2] = x[2]; r[3] = x[3];
    r[4] = 0; r[5] = 0; r[6] = 0; r[7] = 0;
    return r;
}

// async global -> LDS, 16 bytes per lane (dest must be wave-uniform base + lane*16)
__device__ __forceinline__ void gload16(const unsigned char* g, unsigned char* l) {
    __builtin_amdgcn_global_load_lds(
        (__attribute__((address_space(1))) void*)(void*)g,
        (__attribute__((address_space(3))) void*)l, 16, 0, 0);
}

// ---- fp4 MFMA GEMM: C[M,N] = A * B^T, A/B packed nibbles K-major ----
// 256x256 tile, BK=256 (128 B/row), 8 waves 2Mx4N, wave tile 128x64 (4x2 of 32x32x64).
// LDS layout per tile: row r (0..255), 16B granule slot s (0..7) at r*128 + s*16,
// holding global k-granule (s ^ (r&7)) — bank-conflict-free frag reads, and the
// global SOURCE is pre-swizzled so global_load_lds' linear dest yields this layout.
__global__ __launch_bounds__(512, 2) void bgemm_fp4(const unsigned char* __restrict__ A,
                                                    const unsigned char* __restrict__ B,
                                                    float* __restrict__ C) {
    __shared__ __align__(16) unsigned char lds[2 * BUFB];   // 128 KB

    const int tid  = threadIdx.x;
    const int lane = tid & 63;
    const int wave = tid >> 6;   // 0..7
    const int wm   = wave >> 2;  // 0..1 (M)
    const int wn   = wave & 3;   // 0..3 (N)
    const int l31  = lane & 31;
    const int lhi  = lane >> 5;

    const int m0 = blockIdx.y * 256;
    const int n0 = blockIdx.x * 256;

    v16f acc[4][2] = {};

    // Staging: lane's 16B granule g = i*512 + tid; LDS dest = g*16 (linear per wave);
    // global source row = g>>3, k-granule = (g&7) ^ (row&7).
    const unsigned char* gA[4];
    const unsigned char* gB[4];
    int dstOff[4];
#pragma unroll
    for (int i = 0; i < 4; ++i) {
        int g   = i * 512 + tid;
        int row = g >> 3;
        int kc  = (g & 7) ^ (row & 7);
        gA[i] = A + (size_t)(m0 + row) * KB2 + kc * 16;
        gB[i] = B + (size_t)(n0 + row) * KB2 + kc * 16;
        dstOff[i] = g * 16;
    }

    // Fragment read offsets: mfma k-step ks needs k-granule 2*ks + lhi of its row.
    int offA[4][4], offB[4][2];
#pragma unroll
    for (int ks = 0; ks < 4; ++ks) {
#pragma unroll
        for (int tm = 0; tm < 4; ++tm) {
            int r  = wm * 128 + tm * 32 + l31;
            int kc = (2 * ks + lhi) ^ (r & 7);
            offA[ks][tm] = r * BKB + kc * 16;
        }
#pragma unroll
        for (int tn = 0; tn < 2; ++tn) {
            int r  = wn * 64 + tn * 32 + l31;
            int kc = (2 * ks + lhi) ^ (r & 7);
            offB[ks][tn] = r * BKB + kc * 16;
        }
    }

    auto stage = [&](int kt, int b) {
        unsigned char* s = lds + b * BUFB;
        const size_t ko = (size_t)kt * BKB;
#pragma unroll
        for (int i = 0; i < 4; ++i) {
            gload16(gA[i] + ko, s + dstOff[i]);
            gload16(gB[i] + ko, s + TILEB + dstOff[i]);
        }
    };

    auto compute = [&](int b) {
        const unsigned char* sA = lds + b * BUFB;
        const unsigned char* sB = sA + TILEB;
#pragma unroll
        for (int ks = 0; ks < 4; ++ks) {
            v4i a4[4], b4[2];
#pragma unroll
            for (int tm = 0; tm < 4; ++tm) a4[tm] = *(const v4i*)(sA + offA[ks][tm]);
#pragma unroll
            for (int tn = 0; tn < 2; ++tn) b4[tn] = *(const v4i*)(sB + offB[ks][tn]);
#pragma unroll
            for (int tm = 0; tm < 4; ++tm)
#pragma unroll
                for (int tn = 0; tn < 2; ++tn)
                    acc[tm][tn] = __builtin_amdgcn_mfma_scale_f32_32x32x64_f8f6f4(
                        widen(a4[tm]), widen(b4[tn]), acc[tm][tn],
                        4, 4,                  // cbsz=FP4, blgp=FP4
                        0, 0x7F7F7F7F,         // opsel_a, scale_a (e8m0 1.0)
                        0, 0x7F7F7F7F);        // opsel_b, scale_b
        }
    };

    // Pipeline: stage(kt+1) is issued right after the barrier that ends iter kt-1,
    // and is waited by the NEXT __syncthreads' implicit vmcnt(0) — a full compute
    // phase (32 mfma + 24 ds_read) of latency cover.
    stage(0, 0);
    for (int kt = 0; kt < NKT; ++kt) {
        __syncthreads();
        if (kt + 1 < NKT) stage(kt + 1, (kt + 1) & 1);
        compute(kt & 1);
    }

    // Epilogue: C/D 32x32 layout: col = lane&31, row = (r&3) + 8*(r>>2) + 4*lhi.
    // Nontemporal: C is streamed once; keep packed operands resident in L2/L3.
#pragma unroll
    for (int tm = 0; tm < 4; ++tm) {
#pragma unroll
        for (int tn = 0; tn < 2; ++tn) {
            const int col  = n0 + wn * 64 + tn * 32 + l31;
            const int rowb = m0 + wm * 128 + tm * 32 + 4 * lhi;
#pragma unroll
            for (int r = 0; r < 16; ++r) {
                int row = rowb + (r & 3) + 8 * (r >> 2);
                __builtin_nontemporal_store(acc[tm][tn][r], &C[(size_t)row * N_DIM + col]);
            }
        }
    }
}

extern "C" void kernel_launch(void* const* d_in, const int* in_sizes, int n_in,
                              void* d_out, int out_size, void* d_ws, size_t ws_size,
                              hipStream_t stream) {
    const float* x = (const float*)d_in[0];   // [8192, 4096]
    const float* w = (const float*)d_in[1];   // [4096, 4096]
    float* out = (float*)d_out;               // [8192, 4096]

    unsigned char* xq = (unsigned char*)d_ws;                 // 16 MB packed x
    unsigned char* wq = xq + (size_t)M_DIM * KB2;             // 8 MB packed wT

    // 32768 blocks pack x + 2048 blocks pack wT, one dispatch
    pack_both<<<dim3(32768 + 2048), dim3(256), 0, stream>>>(
        x, (unsigned short*)xq, w, wq);
    bgemm_fp4<<<dim3(N_DIM / 256, M_DIM / 256), dim3(512), 0, stream>>>(xq, wq, out);
}